// Round 1
// baseline (214.662 us; speedup 1.0000x reference)
//
#include <hip/hip_runtime.h>
#include <math.h>

constexpr int B = 16, S = 512, D = 1024, H = 16, DH = 64;
constexpr int BH = B * H;        // 256

typedef short bf16x8 __attribute__((ext_vector_type(8)));
typedef float f32x4  __attribute__((ext_vector_type(4)));

__device__ __forceinline__ unsigned short f2bf(float f) {
    unsigned u = __float_as_uint(f);
    u += 0x7fff + ((u >> 16) & 1);   // RNE
    return (unsigned short)(u >> 16);
}

// ---------------------------------------------------------------------------
// x fp32 [B*S][D] -> bf16
// ---------------------------------------------------------------------------
__global__ __launch_bounds__(256) void convert_x(
    const float* __restrict__ x, unsigned short* __restrict__ xb)
{
    int i = blockIdx.x * 256 + threadIdx.x;
    float4 v = ((const float4*)x)[i];
    ushort4 o;
    o.x = f2bf(v.x); o.y = f2bf(v.y); o.z = f2bf(v.z); o.w = f2bf(v.w);
    ((ushort4*)xb)[i] = o;
}

// ---------------------------------------------------------------------------
// W [3][H][D][DH] fp32 -> WbT [3][H][DH][D] bf16 == row-major [3072][1024]
// ---------------------------------------------------------------------------
__global__ __launch_bounds__(256) void convert_w(
    const float* __restrict__ Wq, const float* __restrict__ Wk,
    const float* __restrict__ Wv, unsigned short* __restrict__ WbT)
{
    __shared__ float tile[64][65];
    const int d0 = blockIdx.x * 64;
    const int h = blockIdx.y, m = blockIdx.z;
    const float* W = ((m == 0) ? Wq : (m == 1) ? Wk : Wv) + (size_t)h * D * DH;
    const int t = threadIdx.x;
    {
        int e = t & 63, dr = t >> 6;
        #pragma unroll
        for (int i = 0; i < 16; ++i) {
            int d = dr * 16 + i;
            tile[d][e] = W[(size_t)(d0 + d) * DH + e];
        }
    }
    __syncthreads();
    {
        int d = t & 63, er = t >> 6;
        unsigned short* out = WbT + (size_t)(m * H + h) * DH * D;
        #pragma unroll
        for (int i = 0; i < 16; ++i) {
            int e = er * 16 + i;
            out[(size_t)e * D + d0 + d] = f2bf(tile[d][e]);
        }
    }
}

// ---------------------------------------------------------------------------
// Fused QKV projection, 8-phase pipelined (T3+T4+T5 on top of existing T2):
// C[8192][3072] = xb . WbT^T. BM=BN=256, BK=64, 8 waves (2x4), wave tile
// 128x64 (8x4 frags of 16x16x32). LDS 128 KiB: 2 dbuf x (A 256x64 + B 256x64)
// bf16, XOR-swizzled (g ^ (row&7)). Per 8-phase iteration = 2 K-tiles;
// each phase: {ds_read subtile | stage 1 half-tile (2 gload_lds) | barrier |
// lgkmcnt(0) | setprio(1) 16xMFMA setprio(0) | barrier}; counted vmcnt(4)
// only at phases 4 and 8 (vmcnt(8) prologue, vmcnt(0) tail).
// Region-safety: A-halves last read ph1/ph2 -> staged ph3/ph4; B-halves last
// read ph1/ph3 -> staged next-tile ph1/ph2 (all fenced by lgkm+barrier).
// q scaled by (1/sqrt(D))*log2e; v written transposed [bh][DH][S].
// ---------------------------------------------------------------------------
#define VMC8  asm volatile("s_waitcnt vmcnt(8)" ::: "memory")
#define VMC4  asm volatile("s_waitcnt vmcnt(4)" ::: "memory")
#define VMC0  asm volatile("s_waitcnt vmcnt(0)" ::: "memory")
#define LGKM0 asm volatile("s_waitcnt lgkmcnt(0)" ::: "memory")
#define BARR  __builtin_amdgcn_s_barrier()

__device__ __forceinline__ void stage_half(
    const unsigned short* __restrict__ src, int grow0, int k0,
    unsigned short* dst, int t)
{
    // half-tile = 128 rows x 64 k (16 KB) = 2 gload_lds x 512 threads x 16 B
    #pragma unroll
    for (int r = 0; r < 2; ++r) {
        int row = r * 64 + (t >> 3);
        int gg = (t & 7) ^ (row & 7);          // pre-swizzled global source
        __builtin_amdgcn_global_load_lds(
            (const __attribute__((address_space(1))) void*)
                (src + (size_t)(grow0 + row) * 1024 + k0 + gg * 8),
            (__attribute__((address_space(3))) void*)(dst + r * 4096 + t * 8),
            16, 0, 0);
    }
}

template<int MODE>   // 0 = first iter, 1 = steady-state, 2 = last iter
__device__ __forceinline__ void kiter(
    const unsigned short* __restrict__ xb,
    const unsigned short* __restrict__ WbT,
    unsigned short* As0, unsigned short* Bs0,
    f32x4 (&acc)[8][4], int kb,
    int r0, int n0, int t, int wr, int wc, int lane15, int quad)
{
    #pragma unroll
    for (int half = 0; half < 2; ++half) {
        const unsigned short* Ab = As0 + half * 16384;   // compute buf = half
        const unsigned short* Bb = Bs0 + half * 16384;
        unsigned short* AsT = half ? As0 + 16384 : As0;  // A stages: tile kb/64+2+half
        unsigned short* BsT = half ? Bs0 : Bs0 + 16384;  // B stages: tile kb/64+1+half
        const int arow = wr * 128, brow = wc * 64;
        const int kB = kb + (1 + half) * 64;
        const int kA = kb + (2 + half) * 64;
        const bool doB = !(MODE == 0 && half == 0) && !(MODE == 2 && half == 1);
        const bool doA = (MODE != 2);

        bf16x8 a0[4][2], a1[4][2], b0[2][2], b1[2][2];

        // -------- phase 1: ds A(m0)+B(n0); stage B-half0; mfma m0.n0 --------
        #pragma unroll
        for (int mt = 0; mt < 4; ++mt)
            #pragma unroll
            for (int ks = 0; ks < 2; ++ks) {
                int rl = arow + mt * 16 + lane15, gk = ks * 4 + quad;
                a0[mt][ks] = *(const bf16x8*)(Ab + rl * 64 + (gk ^ (rl & 7)) * 8);
            }
        #pragma unroll
        for (int nt = 0; nt < 2; ++nt)
            #pragma unroll
            for (int ks = 0; ks < 2; ++ks) {
                int rl = brow + nt * 16 + lane15, gk = ks * 4 + quad;
                b0[nt][ks] = *(const bf16x8*)(Bb + rl * 64 + (gk ^ (rl & 7)) * 8);
            }
        if (doB) stage_half(WbT, n0, kB, BsT, t);
        BARR; LGKM0;
        __builtin_amdgcn_s_setprio(1);
        #pragma unroll
        for (int mt = 0; mt < 4; ++mt)
            #pragma unroll
            for (int nt = 0; nt < 2; ++nt) {
                acc[mt][nt] = __builtin_amdgcn_mfma_f32_16x16x32_bf16(
                    a0[mt][0], b0[nt][0], acc[mt][nt], 0, 0, 0);
                acc[mt][nt] = __builtin_amdgcn_mfma_f32_16x16x32_bf16(
                    a0[mt][1], b0[nt][1], acc[mt][nt], 0, 0, 0);
            }
        __builtin_amdgcn_s_setprio(0);
        BARR;

        // -------- phase 2: ds A(m1); stage B-half1; mfma m1.n0 --------
        #pragma unroll
        for (int mt = 0; mt < 4; ++mt)
            #pragma unroll
            for (int ks = 0; ks < 2; ++ks) {
                int rl = arow + 64 + mt * 16 + lane15, gk = ks * 4 + quad;
                a1[mt][ks] = *(const bf16x8*)(Ab + rl * 64 + (gk ^ (rl & 7)) * 8);
            }
        if (doB) stage_half(WbT, n0 + 128, kB, BsT + 8192, t);
        BARR; LGKM0;
        __builtin_amdgcn_s_setprio(1);
        #pragma unroll
        for (int mt = 0; mt < 4; ++mt)
            #pragma unroll
            for (int nt = 0; nt < 2; ++nt) {
                acc[4 + mt][nt] = __builtin_amdgcn_mfma_f32_16x16x32_bf16(
                    a1[mt][0], b0[nt][0], acc[4 + mt][nt], 0, 0, 0);
                acc[4 + mt][nt] = __builtin_amdgcn_mfma_f32_16x16x32_bf16(
                    a1[mt][1], b0[nt][1], acc[4 + mt][nt], 0, 0, 0);
            }
        __builtin_amdgcn_s_setprio(0);
        BARR;

        // -------- phase 3: ds B(n1); stage A-half0; mfma m1.n1 --------
        #pragma unroll
        for (int j = 0; j < 2; ++j)
            #pragma unroll
            for (int ks = 0; ks < 2; ++ks) {
                int rl = brow + 32 + j * 16 + lane15, gk = ks * 4 + quad;
                b1[j][ks] = *(const bf16x8*)(Bb + rl * 64 + (gk ^ (rl & 7)) * 8);
            }
        if (doA) stage_half(xb, r0, kA, AsT, t);
        BARR; LGKM0;
        __builtin_amdgcn_s_setprio(1);
        #pragma unroll
        for (int mt = 0; mt < 4; ++mt)
            #pragma unroll
            for (int j = 0; j < 2; ++j) {
                acc[4 + mt][2 + j] = __builtin_amdgcn_mfma_f32_16x16x32_bf16(
                    a1[mt][0], b1[j][0], acc[4 + mt][2 + j], 0, 0, 0);
                acc[4 + mt][2 + j] = __builtin_amdgcn_mfma_f32_16x16x32_bf16(
                    a1[mt][1], b1[j][1], acc[4 + mt][2 + j], 0, 0, 0);
            }
        __builtin_amdgcn_s_setprio(0);
        BARR;

        // -------- phase 4: stage A-half1; mfma m0.n1; counted vmcnt --------
        if (doA) stage_half(xb, r0 + 128, kA, AsT + 8192, t);
        BARR; LGKM0;
        __builtin_amdgcn_s_setprio(1);
        #pragma unroll
        for (int mt = 0; mt < 4; ++mt)
            #pragma unroll
            for (int j = 0; j < 2; ++j) {
                acc[mt][2 + j] = __builtin_amdgcn_mfma_f32_16x16x32_bf16(
                    a0[mt][0], b1[j][0], acc[mt][2 + j], 0, 0, 0);
                acc[mt][2 + j] = __builtin_amdgcn_mfma_f32_16x16x32_bf16(
                    a0[mt][1], b1[j][1], acc[mt][2 + j], 0, 0, 0);
            }
        __builtin_amdgcn_s_setprio(0);
        // end-of-half wait: guarantee next compute tile fully landed,
        // keep the newest 4 loads (next prefetch) in flight.
        if (half == 0) { if (MODE == 2) { VMC0; } else { VMC4; } }
        else           { if (MODE != 2) { VMC4; } }
        BARR;
    }
}

__global__ __launch_bounds__(512, 2) void qkv_gemm(
    const unsigned short* __restrict__ xb,
    const unsigned short* __restrict__ WbT,
    unsigned short* __restrict__ qkvb)
{
    __shared__ unsigned short As[2 * 16384];   // 64 KB: 2 bufs x 256x64 bf16
    __shared__ unsigned short Bs[2 * 16384];   // 64 KB

    const int t = threadIdx.x;
    const int w = t >> 6;
    const int wr = w >> 2, wc = w & 3;
    const int L = t & 63;
    const int lane15 = L & 15;
    const int quad = L >> 4;

    const int r0 = blockIdx.x * 256;   // global row (b*S+s)
    const int n0 = blockIdx.y * 256;   // global col in [0, 3072)

    f32x4 acc[8][4] = {};

    // prologue: stage tiles 0 (buf0) and 1 (buf1): 16 loads/wave
    stage_half(xb,  r0,       0,  As,                t);
    stage_half(xb,  r0 + 128, 0,  As + 8192,         t);
    stage_half(WbT, n0,       0,  Bs,                t);
    stage_half(WbT, n0 + 128, 0,  Bs + 8192,         t);
    stage_half(xb,  r0,       64, As + 16384,        t);
    stage_half(xb,  r0 + 128, 64, As + 16384 + 8192, t);
    stage_half(WbT, n0,       64, Bs + 16384,        t);
    stage_half(WbT, n0 + 128, 64, Bs + 16384 + 8192, t);
    VMC8;          // tile 0 landed, tile 1's 8 loads still in flight
    BARR;

    kiter<0>(xb, WbT, As, Bs, acc, 0, r0, n0, t, wr, wc, lane15, quad);
    #pragma unroll 1
    for (int it = 1; it < 7; ++it)
        kiter<1>(xb, WbT, As, Bs, acc, it * 128, r0, n0, t, wr, wc, lane15, quad);
    kiter<2>(xb, WbT, As, Bs, acc, 896, r0, n0, t, wr, wc, lane15, quad);

    // epilogue
    const int m  = n0 >> 10;                 // uniform per block
    const int h  = ((n0 >> 6) + wc) & 15;    // one head per wave
    const int bb_ = r0 >> 9;                 // batch (256-row block never straddles)
    const int s0 = (r0 & 511) + wr * 128;

    if (m == 2) {
        unsigned short* outv = qkvb + ((size_t)(2 * BH) + (bb_ * H + h)) * (size_t)(S * DH);
        #pragma unroll
        for (int mt = 0; mt < 8; ++mt) {
            int srow = s0 + mt * 16 + quad * 4;
            #pragma unroll
            for (int nt = 0; nt < 4; ++nt) {
                int e = nt * 16 + lane15;
                ushort4 pk;
                pk.x = f2bf(acc[mt][nt][0]);
                pk.y = f2bf(acc[mt][nt][1]);
                pk.z = f2bf(acc[mt][nt][2]);
                pk.w = f2bf(acc[mt][nt][3]);
                *(ushort4*)(outv + (size_t)e * S + srow) = pk;
            }
        }
    } else {
        const float sc = (m == 0) ? 0.04508422002778011f : 1.0f; // (1/32)*log2e
        unsigned short* out = qkvb + ((size_t)m * BH + (bb_ * H + h)) * (size_t)(S * DH);
        #pragma unroll
        for (int mt = 0; mt < 8; ++mt) {
            #pragma unroll
            for (int nt = 0; nt < 4; ++nt) {
                int e = nt * 16 + lane15;
                #pragma unroll
                for (int r = 0; r < 4; ++r) {
                    int srow = s0 + mt * 16 + quad * 4 + r;
                    out[(size_t)srow * DH + e] = f2bf(acc[mt][nt][r] * sc);
                }
            }
        }
    }
}

// ---------------------------------------------------------------------------
// Flash attention v2: S^T trick — compute S^T = K.Q^T (swap MFMA operands),
// stage Ks with key-permuted rows g(r) so each lane's exp2'd C-registers pack
// IN-LANE into the PV B-fragment (P never touches LDS; no shuffles).
//   g(r) = r[5]*32 | r[3:2]*8 | r[4]*4 | r[1:0]   (bijection on [0,64))
// Per-lane row-sums (one q-row per lane per mt), quad-reduce once at the end.
// O comes out transposed (rows=dh) -> float4 epilogue stores.
// Grid (S/128, B*H), 4 waves; wave owns 32 q-rows. K-tile 64. LDS 32 KB.
// ---------------------------------------------------------------------------
__global__ __launch_bounds__(256) void attn_mfma(
    const unsigned short* __restrict__ qkvb, float* __restrict__ out)
{
    __shared__ unsigned short Qs[128 * 64];   // 16 KB
    __shared__ unsigned short Ks[64 * 64];    // 8 KB  (key rows permuted by g)
    __shared__ unsigned short Vt[64 * 64];    // 8 KB  rows = dh, cols = key (natural)

    const int t = threadIdx.x;
    const int w = t >> 6;
    const int L = t & 63;
    const int lane15 = L & 15;
    const int quad = L >> 4;
    const int lrow8 = L >> 3;
    const int lg = L & 7;
    const int qr0 = blockIdx.x * 128;
    const int bh = blockIdx.y;
    const int b = bh >> 4, h = bh & 15;

    const unsigned short* qb = qkvb + (size_t)bh * S * DH;
    const unsigned short* kb = qkvb + (size_t)(BH + bh) * S * DH;
    const unsigned short* vt = qkvb + (size_t)(2 * BH + bh) * S * DH; // [64][512]

    // stage Q once: wave w stages rows [w*32, w*32+32)
    #pragma unroll
    for (int i = 0; i < 4; ++i) {
        int base = w * 32 + i * 8;
        int r = base + lrow8;
        int gg = lg ^ (r & 7);
        const unsigned short* gp = qb + (size_t)(qr0 + r) * DH + gg * 8;
        __builtin_amdgcn_global_load_lds(
            (const __attribute__((address_space(1))) void*)gp,
            (__attribute__((address_space(3))) void*)(Qs + base * 64),
            16, 0, 0);
    }

    f32x4 o[2][4] = {};                  // rows = dh-slot, col = qrow(lane15)
    float plsum[2] = {0.f, 0.f};
    bf16x8 qf[2][2];

    for (int kt = 0; kt < S; kt += 64) {
        // stage K tile (rows permuted by g) and Vt tile (natural)
        #pragma unroll
        for (int i = 0; i < 2; ++i) {
            int base = (w * 2 + i) * 8;
            int r = base + lrow8;                       // LDS row 0..63
            int gr = (r & 32) | ((r & 12) << 1) | ((r & 16) >> 2) | (r & 3);
            int gg = lg ^ (r & 7);
            const unsigned short* gpk = kb + (size_t)(kt + gr) * DH + gg * 8;
            __builtin_amdgcn_global_load_lds(
                (const __attribute__((address_space(1))) void*)gpk,
                (__attribute__((address_space(3))) void*)(Ks + base * 64),
                16, 0, 0);
            const unsigned short* gpv = vt + (size_t)r * S + kt + gg * 8;
            __builtin_amdgcn_global_load_lds(
                (const __attribute__((address_space(1))) void*)gpv,
                (__attribute__((address_space(3))) void*)(Vt + base * 64),
                16, 0, 0);
        }
        __syncthreads();

        if (kt == 0) {
            #pragma unroll
            for (int mt = 0; mt < 2; ++mt)
                #pragma unroll
                for (int ks = 0; ks < 2; ++ks) {
                    int ml = w * 32 + mt * 16 + lane15;
                    int gk = ks * 4 + quad;
                    qf[mt][ks] = *(const bf16x8*)(Qs + ml * 64 + ((gk ^ (lane15 & 7)) * 8));
                }
        }

        // ---- S^T = K . Q^T : C row = key-slot (quad*4+reg), col = qrow ----
        f32x4 st[2][4] = {};
        #pragma unroll
        for (int ks = 0; ks < 2; ++ks) {
            int gk = ks * 4 + quad;
            bf16x8 kf[4];
            #pragma unroll
            for (int ct = 0; ct < 4; ++ct) {
                int kr = ct * 16 + lane15;
                kf[ct] = *(const bf16x8*)(Ks + kr * 64 + ((gk ^ (lane15 & 7)) * 8));
            }
            #pragma unroll
            for (int mt = 0; mt < 2; ++mt)
                #pragma unroll
                for (int ct = 0; ct < 4; ++ct)
                    st[mt][ct] = __builtin_amdgcn_mfma_f32_16x16x32_bf16(
                        kf[ct], qf[mt][ks], st[mt][ct], 0, 0, 0);
        }

        // ---- p = exp2(s); pack in-lane into PV B-fragments; row partials ----
        bf16x8 pB[2][2];
        #pragma unroll
        for (int mt = 0; mt < 2; ++mt) {
            float rs = 0.f;
            #pragma unroll
            for (int ct = 0; ct < 4; ++ct) {
                float p0 = exp2f(st[mt][ct][0]);
                float p1 = exp2f(st[mt][ct][1]);
                float p2 = exp2f(st[mt][ct][2]);
                float p3 = exp2f(st[mt][ct][3]);
                rs += (p0 + p1) + (p2 + p3);
                int hi = (ct & 1) * 4;
                pB[mt][ct >> 1][hi + 0] = (short)f2bf(p0);
                pB[mt][ct >> 1][hi + 1] = (short)f2bf(p1);
                pB[mt][ct >> 1][hi + 2] = (short)f2bf(p2);
                pB[mt][ct >> 1][hi + 3] = (short)f2bf(p3);
            }
            plsum[mt] += rs;
        }

        // ---- O^T += V^T . P^T  (A = Vt rows, B = in-register P) ----
        #pragma unroll
        for (int ks = 0; ks < 2; ++ks) {
            int gk = ks * 4 + quad;
            bf16x8 vf[4];
            #pragma unroll
            for (int nt = 0; nt < 4; ++nt) {
                int dh = nt * 16 + lane15;
                vf[nt] = *(const bf16x8*)(Vt + dh * 64 + ((gk ^ (lane15 & 7)) * 8));
            }
            #pragma unroll
            for (int mt = 0; mt < 2; ++mt)
                #pragma unroll
                for (int nt = 0; nt < 4; ++nt)
                    o[mt][nt] = __builtin_amdgcn_mfma_f32_16x16x32_bf16(
                        vf[nt], pB[mt][ks], o[mt][nt], 0, 0, 0);
        }
        __syncthreads();
    }

    // epilogue: quad-reduce row sums, normalize, float4 stores (4 consec dh)
    #pragma unroll
    for (int mt = 0; mt < 2; ++mt) {
        float l = plsum[mt];
        l += __shfl_xor(l, 16, 64);
        l += __shfl_xor(l, 32, 64);
        float inv = 1.0f / l;
        int srow = qr0 + w * 32 + mt * 16 + lane15;
        float* op = out + (size_t)(b * S + srow) * D + h * DH;
        #pragma unroll
        for (int nt = 0; nt < 4; ++nt) {
            float4 v;
            v.x = o[mt][nt][0] * inv;
            v.y = o[mt][nt][1] * inv;
            v.z = o[mt][nt][2] * inv;
            v.w = o[mt][nt][3] * inv;
            *(float4*)(op + nt * 16 + quad * 4) = v;
        }
    }
}

extern "C" void kernel_launch(void* const* d_in, const int* in_sizes, int n_in,
                              void* d_out, int out_size, void* d_ws, size_t ws_size,
                              hipStream_t stream) {
    const float* x  = (const float*)d_in[0];
    const float* Wq = (const float*)d_in[1];
    const float* Wk = (const float*)d_in[2];
    const float* Wv = (const float*)d_in[3];
    float* outp = (float*)d_out;

    // workspace: [0, 50331648) qkvb bf16 (q,k row-major; v transposed)
    //            [50331648, 67108864) xb bf16; [67108864, 73400320) WbT bf16
    unsigned short* qkvb = (unsigned short*)d_ws;
    unsigned short* xb   = (unsigned short*)((char*)d_ws + 50331648);
    unsigned short* WbT  = (unsigned short*)((char*)d_ws + 67108864);

    convert_x<<<dim3((B * S * D / 4) / 256), 256, 0, stream>>>(x, xb);
    convert_w<<<dim3(D / 64, H, 3), 256, 0, stream>>>(Wq, Wk, Wv, WbT);
    qkv_gemm<<<dim3(B * S / 256, 3 * H * DH / 256), 512, 0, stream>>>(xb, WbT, qkvb);
    attn_mfma<<<dim3(S / 128, BH), 256, 0, stream>>>(qkvb, outp);
}

// Round 2
// 196.764 us; speedup vs baseline: 1.0910x; 1.0910x over previous
//
#include <hip/hip_runtime.h>
#include <math.h>

constexpr int B = 16, S = 512, D = 1024, H = 16, DH = 64;
constexpr int BH = B * H;        // 256

typedef short bf16x8 __attribute__((ext_vector_type(8)));
typedef float f32x4  __attribute__((ext_vector_type(4)));

__device__ __forceinline__ unsigned short f2bf(float f) {
    unsigned u = __float_as_uint(f);
    u += 0x7fff + ((u >> 16) & 1);   // RNE
    return (unsigned short)(u >> 16);
}

#define VMC0  asm volatile("s_waitcnt vmcnt(0)" ::: "memory")
#define BARR  __builtin_amdgcn_s_barrier()

// ---------------------------------------------------------------------------
// x fp32 [B*S][D] -> bf16
// ---------------------------------------------------------------------------
__global__ __launch_bounds__(256) void convert_x(
    const float* __restrict__ x, unsigned short* __restrict__ xb)
{
    int i = blockIdx.x * 256 + threadIdx.x;
    float4 v = ((const float4*)x)[i];
    ushort4 o;
    o.x = f2bf(v.x); o.y = f2bf(v.y); o.z = f2bf(v.z); o.w = f2bf(v.w);
    ((ushort4*)xb)[i] = o;
}

// ---------------------------------------------------------------------------
// W [3][H][D][DH] fp32 -> WbT [3][H][DH][D] bf16 == row-major [3072][1024]
// ---------------------------------------------------------------------------
__global__ __launch_bounds__(256) void convert_w(
    const float* __restrict__ Wq, const float* __restrict__ Wk,
    const float* __restrict__ Wv, unsigned short* __restrict__ WbT)
{
    __shared__ float tile[64][65];
    const int d0 = blockIdx.x * 64;
    const int h = blockIdx.y, m = blockIdx.z;
    const float* W = ((m == 0) ? Wq : (m == 1) ? Wk : Wv) + (size_t)h * D * DH;
    const int t = threadIdx.x;
    {
        int e = t & 63, dr = t >> 6;
        #pragma unroll
        for (int i = 0; i < 16; ++i) {
            int d = dr * 16 + i;
            tile[d][e] = W[(size_t)(d0 + d) * DH + e];
        }
    }
    __syncthreads();
    {
        int d = t & 63, er = t >> 6;
        unsigned short* out = WbT + (size_t)(m * H + h) * DH * D;
        #pragma unroll
        for (int i = 0; i < 16; ++i) {
            int e = er * 16 + i;
            out[(size_t)e * D + d0 + d] = f2bf(tile[d][e]);
        }
    }
}

// ---------------------------------------------------------------------------
// Fused QKV projection: C[8192][3072] = xb . WbT^T, 128x128 block tile,
// 4 waves in 2x2, each 64x64 (4x4 MFMA 16x16x32 bf16), BK=64, 32 KB LDS.
// (Round-0 proven version: 73.7 us. The 256^2 8-phase port spilled to
//  scratch — WRITE_SIZE +23 MB — and regressed; reverted.)
// q scaled by (1/sqrt(D))*log2e; v written transposed [bh][DH][S].
// ---------------------------------------------------------------------------
__global__ __launch_bounds__(256) void qkv_gemm(
    const unsigned short* __restrict__ xb,
    const unsigned short* __restrict__ WbT,
    unsigned short* __restrict__ qkvb)
{
    __shared__ unsigned short As[128 * 64];   // 16 KB, swizzled g^(row&7)
    __shared__ unsigned short Bs[128 * 64];   // 16 KB

    const int t = threadIdx.x;
    const int w = t >> 6;
    const int wr = w >> 1, wc = w & 1;
    const int L = t & 63;
    const int lane15 = L & 15;
    const int quad = L >> 4;
    const int lrow8 = L >> 3;
    const int lg = L & 7;

    const int r0 = blockIdx.x * 128;   // global row (b*S+s)
    const int n0 = blockIdx.y * 128;   // global col in [0, 3072)

    f32x4 acc[4][4] = {};

    for (int k0 = 0; k0 < D; k0 += 64) {
        #pragma unroll
        for (int i = 0; i < 4; ++i) {
            int c = w * 4 + i;
            int r = c * 8 + lrow8;
            int gg = lg ^ (r & 7);
            const unsigned short* gp = xb + (size_t)(r0 + r) * D + k0 + gg * 8;
            __builtin_amdgcn_global_load_lds(
                (const __attribute__((address_space(1))) void*)gp,
                (__attribute__((address_space(3))) void*)(As + c * 512),
                16, 0, 0);
            const unsigned short* gq = WbT + (size_t)(n0 + r) * D + k0 + gg * 8;
            __builtin_amdgcn_global_load_lds(
                (const __attribute__((address_space(1))) void*)gq,
                (__attribute__((address_space(3))) void*)(Bs + c * 512),
                16, 0, 0);
        }
        __syncthreads();

        #pragma unroll
        for (int ks = 0; ks < 2; ++ks) {
            int gk = ks * 4 + quad;
            bf16x8 a[4], bb[4];
            #pragma unroll
            for (int rt = 0; rt < 4; ++rt) {
                int ml = wr * 64 + rt * 16 + lane15;
                a[rt] = *(const bf16x8*)(As + ml * 64 + ((gk ^ (ml & 7)) * 8));
            }
            #pragma unroll
            for (int ct = 0; ct < 4; ++ct) {
                int nl = wc * 64 + ct * 16 + lane15;
                bb[ct] = *(const bf16x8*)(Bs + nl * 64 + ((gk ^ (nl & 7)) * 8));
            }
            #pragma unroll
            for (int rt = 0; rt < 4; ++rt)
                #pragma unroll
                for (int ct = 0; ct < 4; ++ct)
                    acc[rt][ct] = __builtin_amdgcn_mfma_f32_16x16x32_bf16(
                        a[rt], bb[ct], acc[rt][ct], 0, 0, 0);
        }
        __syncthreads();
    }

    const int m  = n0 >> 10;                 // uniform per block
    const int h  = ((n0 >> 6) + wc) & 15;    // one head per wave
    const int bb_ = r0 >> 9;                 // batch
    const int s0 = (r0 & 511) + wr * 64;

    if (m == 2) {
        unsigned short* outv = qkvb + ((size_t)(2 * BH) + (bb_ * H + h)) * (size_t)(S * DH);
        #pragma unroll
        for (int rt = 0; rt < 4; ++rt) {
            int srow = s0 + rt * 16 + quad * 4;
            #pragma unroll
            for (int ct = 0; ct < 4; ++ct) {
                int e = ct * 16 + lane15;
                ushort4 pk;
                pk.x = f2bf(acc[rt][ct][0]);
                pk.y = f2bf(acc[rt][ct][1]);
                pk.z = f2bf(acc[rt][ct][2]);
                pk.w = f2bf(acc[rt][ct][3]);
                *(ushort4*)(outv + (size_t)e * S + srow) = pk;
            }
        }
    } else {
        const float sc = (m == 0) ? 0.04508422002778011f : 1.0f; // (1/32)*log2e
        unsigned short* out = qkvb + ((size_t)m * BH + (bb_ * H + h)) * (size_t)(S * DH);
        #pragma unroll
        for (int rt = 0; rt < 4; ++rt) {
            #pragma unroll
            for (int ct = 0; ct < 4; ++ct) {
                int e = ct * 16 + lane15;
                #pragma unroll
                for (int r = 0; r < 4; ++r) {
                    int srow = s0 + rt * 16 + quad * 4 + r;
                    out[(size_t)srow * DH + e] = f2bf(acc[rt][ct][r] * sc);
                }
            }
        }
    }
}

// ---------------------------------------------------------------------------
// Flash attention v2, now PIPELINED (T3-minimum + T14 + T5):
// S^T trick — compute S^T = K.Q^T (swap MFMA operands), key-permuted K rows
// g(r) so exp2'd C-registers pack IN-LANE into the PV B-fragment.
//   g(r) = r[5]*32 | r[3:2]*8 | r[4]*4 | r[1:0]
// NEW: K and Vt double-buffered (48 KB LDS). Per iteration: issue next
// tile's global_load_lds FIRST, compute current tile (QK^T + exp + PV)
// underneath (~latency cover), then ONE vmcnt(0) + raw s_barrier — no
// __syncthreads() full-drain mid-iteration. setprio(1) around MFMA
// clusters (m191: +4-7% attn). Safety: buf[nxt]'s last reads (iter i-1)
// are fenced by iter i-1's end barrier before iter i's stage writes.
// Grid (S/128, B*H), 4 waves; wave owns 32 q-rows. K-tile 64.
// ---------------------------------------------------------------------------
__device__ __forceinline__ void stage_kv(
    const unsigned short* __restrict__ kb, const unsigned short* __restrict__ vt,
    int kt, unsigned short* Kd, unsigned short* Vd, int w, int lrow8, int lg)
{
    #pragma unroll
    for (int i = 0; i < 2; ++i) {
        int base = (w * 2 + i) * 8;
        int r = base + lrow8;                       // LDS row 0..63
        int gr = (r & 32) | ((r & 12) << 1) | ((r & 16) >> 2) | (r & 3);
        int gg = lg ^ (r & 7);
        __builtin_amdgcn_global_load_lds(
            (const __attribute__((address_space(1))) void*)
                (kb + (size_t)(kt + gr) * DH + gg * 8),
            (__attribute__((address_space(3))) void*)(Kd + base * 64),
            16, 0, 0);
        __builtin_amdgcn_global_load_lds(
            (const __attribute__((address_space(1))) void*)
                (vt + (size_t)r * S + kt + gg * 8),
            (__attribute__((address_space(3))) void*)(Vd + base * 64),
            16, 0, 0);
    }
}

__global__ __launch_bounds__(256) void attn_mfma(
    const unsigned short* __restrict__ qkvb, float* __restrict__ out)
{
    __shared__ unsigned short Qs[128 * 64];        // 16 KB
    __shared__ unsigned short Ks[2][64 * 64];      // 16 KB (dbuf, rows perm by g)
    __shared__ unsigned short Vt[2][64 * 64];      // 16 KB (dbuf, rows = dh)

    const int t = threadIdx.x;
    const int w = t >> 6;
    const int L = t & 63;
    const int lane15 = L & 15;
    const int quad = L >> 4;
    const int lrow8 = L >> 3;
    const int lg = L & 7;
    const int qr0 = blockIdx.x * 128;
    const int bh = blockIdx.y;
    const int b = bh >> 4, h = bh & 15;

    const unsigned short* qb = qkvb + (size_t)bh * S * DH;
    const unsigned short* kb = qkvb + (size_t)(BH + bh) * S * DH;
    const unsigned short* vt = qkvb + (size_t)(2 * BH + bh) * S * DH; // [64][512]

    // stage Q once: wave w stages rows [w*32, w*32+32)
    #pragma unroll
    for (int i = 0; i < 4; ++i) {
        int base = w * 32 + i * 8;
        int r = base + lrow8;
        int gg = lg ^ (r & 7);
        const unsigned short* gp = qb + (size_t)(qr0 + r) * DH + gg * 8;
        __builtin_amdgcn_global_load_lds(
            (const __attribute__((address_space(1))) void*)gp,
            (__attribute__((address_space(3))) void*)(Qs + base * 64),
            16, 0, 0);
    }
    // stage K/V tile 0 into buf 0, drain everything once, barrier
    stage_kv(kb, vt, 0, &Ks[0][0], &Vt[0][0], w, lrow8, lg);
    VMC0;
    BARR;

    // Q fragments: loaded once, live in registers for the whole kernel
    bf16x8 qf[2][2];
    #pragma unroll
    for (int mt = 0; mt < 2; ++mt)
        #pragma unroll
        for (int ks = 0; ks < 2; ++ks) {
            int ml = w * 32 + mt * 16 + lane15;
            int gk = ks * 4 + quad;
            qf[mt][ks] = *(const bf16x8*)(Qs + ml * 64 + ((gk ^ (lane15 & 7)) * 8));
        }

    f32x4 o[2][4] = {};                  // rows = dh-slot, col = qrow(lane15)
    float plsum[2] = {0.f, 0.f};

    #pragma unroll 2
    for (int kt = 0; kt < S; kt += 64) {
        const int cur = (kt >> 6) & 1;   // compile-time under unroll 2
        const int nxt = cur ^ 1;

        // ---- prefetch next K/V tile FIRST (lands under this iter's compute)
        if (kt + 64 < S)
            stage_kv(kb, vt, kt + 64, &Ks[nxt][0], &Vt[nxt][0], w, lrow8, lg);

        // ---- S^T = K . Q^T : C row = key-slot (quad*4+reg), col = qrow ----
        f32x4 st[2][4] = {};
        #pragma unroll
        for (int ks = 0; ks < 2; ++ks) {
            int gk = ks * 4 + quad;
            bf16x8 kf[4];
            #pragma unroll
            for (int ct = 0; ct < 4; ++ct) {
                int kr = ct * 16 + lane15;
                kf[ct] = *(const bf16x8*)(&Ks[cur][0] + kr * 64 + ((gk ^ (lane15 & 7)) * 8));
            }
            __builtin_amdgcn_s_setprio(1);
            #pragma unroll
            for (int mt = 0; mt < 2; ++mt)
                #pragma unroll
                for (int ct = 0; ct < 4; ++ct)
                    st[mt][ct] = __builtin_amdgcn_mfma_f32_16x16x32_bf16(
                        kf[ct], qf[mt][ks], st[mt][ct], 0, 0, 0);
            __builtin_amdgcn_s_setprio(0);
        }

        // ---- p = exp2(s); pack in-lane into PV B-fragments; row partials ----
        bf16x8 pB[2][2];
        #pragma unroll
        for (int mt = 0; mt < 2; ++mt) {
            float rs = 0.f;
            #pragma unroll
            for (int ct = 0; ct < 4; ++ct) {
                float p0 = exp2f(st[mt][ct][0]);
                float p1 = exp2f(st[mt][ct][1]);
                float p2 = exp2f(st[mt][ct][2]);
                float p3 = exp2f(st[mt][ct][3]);
                rs += (p0 + p1) + (p2 + p3);
                int hi = (ct & 1) * 4;
                pB[mt][ct >> 1][hi + 0] = (short)f2bf(p0);
                pB[mt][ct >> 1][hi + 1] = (short)f2bf(p1);
                pB[mt][ct >> 1][hi + 2] = (short)f2bf(p2);
                pB[mt][ct >> 1][hi + 3] = (short)f2bf(p3);
            }
            plsum[mt] += rs;
        }

        // ---- O^T += V^T . P^T  (A = Vt rows, B = in-register P) ----
        #pragma unroll
        for (int ks = 0; ks < 2; ++ks) {
            int gk = ks * 4 + quad;
            bf16x8 vf[4];
            #pragma unroll
            for (int nt = 0; nt < 4; ++nt) {
                int dh = nt * 16 + lane15;
                vf[nt] = *(const bf16x8*)(&Vt[cur][0] + dh * 64 + ((gk ^ (lane15 & 7)) * 8));
            }
            __builtin_amdgcn_s_setprio(1);
            #pragma unroll
            for (int mt = 0; mt < 2; ++mt)
                #pragma unroll
                for (int nt = 0; nt < 4; ++nt)
                    o[mt][nt] = __builtin_amdgcn_mfma_f32_16x16x32_bf16(
                        vf[nt], pB[mt][ks], o[mt][nt], 0, 0, 0);
            __builtin_amdgcn_s_setprio(0);
        }

        // ---- one wait+barrier per iteration: next tile landed, this
        //      tile's reads (all waves) complete before next iter's stage
        VMC0;
        BARR;
    }

    // epilogue: quad-reduce row sums, normalize, float4 stores (4 consec dh)
    #pragma unroll
    for (int mt = 0; mt < 2; ++mt) {
        float l = plsum[mt];
        l += __shfl_xor(l, 16, 64);
        l += __shfl_xor(l, 32, 64);
        float inv = 1.0f / l;
        int srow = qr0 + w * 32 + mt * 16 + lane15;
        float* op = out + (size_t)(b * S + srow) * D + h * DH;
        #pragma unroll
        for (int nt = 0; nt < 4; ++nt) {
            float4 v;
            v.x = o[mt][nt][0] * inv;
            v.y = o[mt][nt][1] * inv;
            v.z = o[mt][nt][2] * inv;
            v.w = o[mt][nt][3] * inv;
            *(float4*)(op + nt * 16 + quad * 4) = v;
        }
    }
}

extern "C" void kernel_launch(void* const* d_in, const int* in_sizes, int n_in,
                              void* d_out, int out_size, void* d_ws, size_t ws_size,
                              hipStream_t stream) {
    const float* x  = (const float*)d_in[0];
    const float* Wq = (const float*)d_in[1];
    const float* Wk = (const float*)d_in[2];
    const float* Wv = (const float*)d_in[3];
    float* outp = (float*)d_out;

    // workspace: [0, 50331648) qkvb bf16 (q,k row-major; v transposed)
    //            [50331648, 67108864) xb bf16; [67108864, 73400320) WbT bf16
    unsigned short* qkvb = (unsigned short*)d_ws;
    unsigned short* xb   = (unsigned short*)((char*)d_ws + 50331648);
    unsigned short* WbT  = (unsigned short*)((char*)d_ws + 67108864);

    convert_x<<<dim3((B * S * D / 4) / 256), 256, 0, stream>>>(x, xb);
    convert_w<<<dim3(D / 64, H, 3), 256, 0, stream>>>(Wq, Wk, Wv, WbT);
    qkv_gemm<<<dim3(B * S / 128, 3 * H * DH / 128), 256, 0, stream>>>(xb, WbT, qkvb);
    attn_mfma<<<dim3(S / 128, BH), 256, 0, stream>>>(qkvb, outp);
}

// Round 3
// 193.014 us; speedup vs baseline: 1.1122x; 1.0194x over previous
//
#include <hip/hip_runtime.h>
#include <math.h>

constexpr int B = 16, S = 512, D = 1024, H = 16, DH = 64;
constexpr int BH = B * H;        // 256

typedef short bf16x8 __attribute__((ext_vector_type(8)));
typedef float f32x4  __attribute__((ext_vector_type(4)));

__device__ __forceinline__ unsigned short f2bf(float f) {
    unsigned u = __float_as_uint(f);
    u += 0x7fff + ((u >> 16) & 1);   // RNE
    return (unsigned short)(u >> 16);
}

#define VMC0  asm volatile("s_waitcnt vmcnt(0)" ::: "memory")
#define BARR  __builtin_amdgcn_s_barrier()

// ---------------------------------------------------------------------------
// x fp32 [B*S][D] -> bf16
// ---------------------------------------------------------------------------
__global__ __launch_bounds__(256) void convert_x(
    const float* __restrict__ x, unsigned short* __restrict__ xb)
{
    int i = blockIdx.x * 256 + threadIdx.x;
    float4 v = ((const float4*)x)[i];
    ushort4 o;
    o.x = f2bf(v.x); o.y = f2bf(v.y); o.z = f2bf(v.z); o.w = f2bf(v.w);
    ((ushort4*)xb)[i] = o;
}

// ---------------------------------------------------------------------------
// W [3][H][D][DH] fp32 -> WbT [3][H][DH][D] bf16 == row-major [3072][1024]
// ---------------------------------------------------------------------------
__global__ __launch_bounds__(256) void convert_w(
    const float* __restrict__ Wq, const float* __restrict__ Wk,
    const float* __restrict__ Wv, unsigned short* __restrict__ WbT)
{
    __shared__ float tile[64][65];
    const int d0 = blockIdx.x * 64;
    const int h = blockIdx.y, m = blockIdx.z;
    const float* W = ((m == 0) ? Wq : (m == 1) ? Wk : Wv) + (size_t)h * D * DH;
    const int t = threadIdx.x;
    {
        int e = t & 63, dr = t >> 6;
        #pragma unroll
        for (int i = 0; i < 16; ++i) {
            int d = dr * 16 + i;
            tile[d][e] = W[(size_t)(d0 + d) * DH + e];
        }
    }
    __syncthreads();
    {
        int d = t & 63, er = t >> 6;
        unsigned short* out = WbT + (size_t)(m * H + h) * DH * D;
        #pragma unroll
        for (int i = 0; i < 16; ++i) {
            int e = er * 16 + i;
            out[(size_t)e * D + d0 + d] = f2bf(tile[d][e]);
        }
    }
}

// ---------------------------------------------------------------------------
// Fused QKV projection: C[8192][3072] = xb . WbT^T, 128x128 block tile,
// 4 waves in 2x2, each 64x64 (4x4 MFMA 16x16x32 bf16), BK=64, 32 KB LDS.
// NEW this round: q/k epilogue bounces the 64x64 wave tile through LDS
// (wave-private quarter of As/Bs, XOR-swizzled chunks) so every global
// store is a wave-contiguous 1 KB dwordx4 burst — eliminates the scalar
// 2B stores whose partial-line write-allocate RMW accounted for the extra
// ~27 MB FETCH_SIZE (49 MB observed vs 22 MB compulsory input reads).
// q scaled by (1/sqrt(D))*log2e; v written transposed [bh][DH][S].
// ---------------------------------------------------------------------------
__global__ __launch_bounds__(256) void qkv_gemm(
    const unsigned short* __restrict__ xb,
    const unsigned short* __restrict__ WbT,
    unsigned short* __restrict__ qkvb)
{
    __shared__ unsigned short As[128 * 64];   // 16 KB, swizzled g^(row&7)
    __shared__ unsigned short Bs[128 * 64];   // 16 KB

    const int t = threadIdx.x;
    const int w = t >> 6;
    const int wr = w >> 1, wc = w & 1;
    const int L = t & 63;
    const int lane15 = L & 15;
    const int quad = L >> 4;
    const int lrow8 = L >> 3;
    const int lg = L & 7;

    const int r0 = blockIdx.x * 128;   // global row (b*S+s)
    const int n0 = blockIdx.y * 128;   // global col in [0, 3072)

    f32x4 acc[4][4] = {};

    for (int k0 = 0; k0 < D; k0 += 64) {
        #pragma unroll
        for (int i = 0; i < 4; ++i) {
            int c = w * 4 + i;
            int r = c * 8 + lrow8;
            int gg = lg ^ (r & 7);
            const unsigned short* gp = xb + (size_t)(r0 + r) * D + k0 + gg * 8;
            __builtin_amdgcn_global_load_lds(
                (const __attribute__((address_space(1))) void*)gp,
                (__attribute__((address_space(3))) void*)(As + c * 512),
                16, 0, 0);
            const unsigned short* gq = WbT + (size_t)(n0 + r) * D + k0 + gg * 8;
            __builtin_amdgcn_global_load_lds(
                (const __attribute__((address_space(1))) void*)gq,
                (__attribute__((address_space(3))) void*)(Bs + c * 512),
                16, 0, 0);
        }
        __syncthreads();

        #pragma unroll
        for (int ks = 0; ks < 2; ++ks) {
            int gk = ks * 4 + quad;
            bf16x8 a[4], bb[4];
            #pragma unroll
            for (int rt = 0; rt < 4; ++rt) {
                int ml = wr * 64 + rt * 16 + lane15;
                a[rt] = *(const bf16x8*)(As + ml * 64 + ((gk ^ (ml & 7)) * 8));
            }
            #pragma unroll
            for (int ct = 0; ct < 4; ++ct) {
                int nl = wc * 64 + ct * 16 + lane15;
                bb[ct] = *(const bf16x8*)(Bs + nl * 64 + ((gk ^ (nl & 7)) * 8));
            }
            #pragma unroll
            for (int rt = 0; rt < 4; ++rt)
                #pragma unroll
                for (int ct = 0; ct < 4; ++ct)
                    acc[rt][ct] = __builtin_amdgcn_mfma_f32_16x16x32_bf16(
                        a[rt], bb[ct], acc[rt][ct], 0, 0, 0);
        }
        __syncthreads();
    }

    const int m  = n0 >> 10;                 // uniform per block
    const int h  = ((n0 >> 6) + wc) & 15;    // one head per wave
    const int bb_ = r0 >> 9;                 // batch
    const int s0 = (r0 & 511) + wr * 64;

    if (m == 2) {
        unsigned short* outv = qkvb + ((size_t)(2 * BH) + (bb_ * H + h)) * (size_t)(S * DH);
        #pragma unroll
        for (int rt = 0; rt < 4; ++rt) {
            int srow = s0 + rt * 16 + quad * 4;
            #pragma unroll
            for (int ct = 0; ct < 4; ++ct) {
                int e = ct * 16 + lane15;
                ushort4 pk;
                pk.x = f2bf(acc[rt][ct][0]);
                pk.y = f2bf(acc[rt][ct][1]);
                pk.z = f2bf(acc[rt][ct][2]);
                pk.w = f2bf(acc[rt][ct][3]);
                *(ushort4*)(outv + (size_t)e * S + srow) = pk;
            }
        }
    } else {
        const float sc = (m == 0) ? 0.04508422002778011f : 1.0f; // (1/32)*log2e
        // LDS bounce: wave-private 8 KB quarter (main loop done, final
        // __syncthreads() passed, each wave touches only its own region).
        unsigned short* eb = (w < 2) ? (As + w * 4096) : (Bs + (w - 2) * 4096);
        #pragma unroll
        for (int rt = 0; rt < 4; ++rt)
            #pragma unroll
            for (int ct = 0; ct < 4; ++ct) {
                int e = ct * 16 + lane15;
                #pragma unroll
                for (int r = 0; r < 4; ++r) {
                    int row = rt * 16 + quad * 4 + r;
                    eb[row * 64 + (((e >> 3) ^ (row & 7)) * 8) + (e & 7)] =
                        f2bf(acc[rt][ct][r] * sc);
                }
            }
        unsigned short* outq = qkvb + ((size_t)m * BH + (bb_ * H + h)) * (size_t)(S * DH);
        #pragma unroll
        for (int j = 0; j < 8; ++j) {
            int row = j * 8 + lrow8;      // 8 lanes span one full 128 B row
            bf16x8 vv = *(const bf16x8*)(eb + row * 64 + ((lg ^ (row & 7)) * 8));
            *(bf16x8*)(outq + (size_t)(s0 + row) * DH + lg * 8) = vv;
        }
    }
}

// ---------------------------------------------------------------------------
// Flash attention v2, pipelined (T14 done RIGHT this time):
// S^T trick — compute S^T = K.Q^T (swap MFMA operands), key-permuted K rows
// g(r) so exp2'd C-registers pack IN-LANE into the PV B-fragment.
//   g(r) = r[5]*32 | r[3:2]*8 | r[4]*4 | r[1:0]
// Per iteration: read ALL 16 current-tile fragments (ds_read_b128) into
// registers FIRST, sched_barrier(0) to pin order, THEN issue next tile's
// global_load_lds, then compute (QK^T + exp2/cvt_pk + PV) with ~800 cyc
// covering the prefetch, then one vmcnt(0) + s_barrier. (Round-2 issued
// the stage before the ds_reads; hipcc's conservative LDS aliasing inserts
// vmcnt(0) before the reads → zero hiding. Reads-first makes any compiler
// wait redundant with our own end-of-iter VMC0.)
// P->bf16 via inline-asm v_cvt_pk_bf16_f32 (RNE, 2 floats/instr): 16 instrs
// replace ~128 bit-twiddle VALU ops per iteration.
// Grid (S/128, B*H), 4 waves; wave owns 32 q-rows. K-tile 64. LDS 48 KB.
// ---------------------------------------------------------------------------
__device__ __forceinline__ void stage_kv(
    const unsigned short* __restrict__ kb, const unsigned short* __restrict__ vt,
    int kt, unsigned short* Kd, unsigned short* Vd, int w, int lrow8, int lg)
{
    #pragma unroll
    for (int i = 0; i < 2; ++i) {
        int base = (w * 2 + i) * 8;
        int r = base + lrow8;                       // LDS row 0..63
        int gr = (r & 32) | ((r & 12) << 1) | ((r & 16) >> 2) | (r & 3);
        int gg = lg ^ (r & 7);
        __builtin_amdgcn_global_load_lds(
            (const __attribute__((address_space(1))) void*)
                (kb + (size_t)(kt + gr) * DH + gg * 8),
            (__attribute__((address_space(3))) void*)(Kd + base * 64),
            16, 0, 0);
        __builtin_amdgcn_global_load_lds(
            (const __attribute__((address_space(1))) void*)
                (vt + (size_t)r * S + kt + gg * 8),
            (__attribute__((address_space(3))) void*)(Vd + base * 64),
            16, 0, 0);
    }
}

__global__ __launch_bounds__(256) void attn_mfma(
    const unsigned short* __restrict__ qkvb, float* __restrict__ out)
{
    __shared__ unsigned short Qs[128 * 64];        // 16 KB
    __shared__ unsigned short Ks[2][64 * 64];      // 16 KB (dbuf, rows perm by g)
    __shared__ unsigned short Vt[2][64 * 64];      // 16 KB (dbuf, rows = dh)

    const int t = threadIdx.x;
    const int w = t >> 6;
    const int L = t & 63;
    const int lane15 = L & 15;
    const int quad = L >> 4;
    const int lrow8 = L >> 3;
    const int lg = L & 7;
    const int qr0 = blockIdx.x * 128;
    const int bh = blockIdx.y;
    const int b = bh >> 4, h = bh & 15;

    const unsigned short* qb = qkvb + (size_t)bh * S * DH;
    const unsigned short* kb = qkvb + (size_t)(BH + bh) * S * DH;
    const unsigned short* vt = qkvb + (size_t)(2 * BH + bh) * S * DH; // [64][512]

    // stage Q once: wave w stages rows [w*32, w*32+32)
    #pragma unroll
    for (int i = 0; i < 4; ++i) {
        int base = w * 32 + i * 8;
        int r = base + lrow8;
        int gg = lg ^ (r & 7);
        const unsigned short* gp = qb + (size_t)(qr0 + r) * DH + gg * 8;
        __builtin_amdgcn_global_load_lds(
            (const __attribute__((address_space(1))) void*)gp,
            (__attribute__((address_space(3))) void*)(Qs + base * 64),
            16, 0, 0);
    }
    // stage K/V tile 0 into buf 0, drain everything once, barrier
    stage_kv(kb, vt, 0, &Ks[0][0], &Vt[0][0], w, lrow8, lg);
    VMC0;
    BARR;

    // Q fragments: loaded once, live in registers for the whole kernel
    bf16x8 qf[2][2];
    #pragma unroll
    for (int mt = 0; mt < 2; ++mt)
        #pragma unroll
        for (int ks = 0; ks < 2; ++ks) {
            int ml = w * 32 + mt * 16 + lane15;
            int gk = ks * 4 + quad;
            qf[mt][ks] = *(const bf16x8*)(Qs + ml * 64 + ((gk ^ (lane15 & 7)) * 8));
        }

    f32x4 o[2][4] = {};                  // rows = dh-slot, col = qrow(lane15)
    float plsum[2] = {0.f, 0.f};

    #pragma unroll 2
    for (int kt = 0; kt < S; kt += 64) {
        const int cur = (kt >> 6) & 1;   // compile-time under unroll 2
        const int nxt = cur ^ 1;

        // ---- read ALL current-tile fragments into registers FIRST ----
        bf16x8 kf[2][4], vf[2][4];
        #pragma unroll
        for (int ks = 0; ks < 2; ++ks) {
            int gk = ks * 4 + quad;
            #pragma unroll
            for (int ct = 0; ct < 4; ++ct) {
                int kr = ct * 16 + lane15;   // kr&7 == lane15&7
                kf[ks][ct] = *(const bf16x8*)(&Ks[cur][0] + kr * 64 + ((gk ^ (lane15 & 7)) * 8));
                vf[ks][ct] = *(const bf16x8*)(&Vt[cur][0] + kr * 64 + ((gk ^ (lane15 & 7)) * 8));
            }
        }
        __builtin_amdgcn_sched_barrier(0);   // pin: reads above, stage below

        // ---- issue next tile's prefetch (lands under compute below) ----
        if (kt + 64 < S)
            stage_kv(kb, vt, kt + 64, &Ks[nxt][0], &Vt[nxt][0], w, lrow8, lg);

        // ---- S^T = K . Q^T : C row = key-slot (quad*4+reg), col = qrow ----
        f32x4 st[2][4] = {};
        __builtin_amdgcn_s_setprio(1);
        #pragma unroll
        for (int ks = 0; ks < 2; ++ks)
            #pragma unroll
            for (int mt = 0; mt < 2; ++mt)
                #pragma unroll
                for (int ct = 0; ct < 4; ++ct)
                    st[mt][ct] = __builtin_amdgcn_mfma_f32_16x16x32_bf16(
                        kf[ks][ct], qf[mt][ks], st[mt][ct], 0, 0, 0);
        __builtin_amdgcn_s_setprio(0);

        // ---- p = exp2(s); cvt_pk into PV B-fragments; row partials ----
        bf16x8 pB[2][2];
        #pragma unroll
        for (int mt = 0; mt < 2; ++mt) {
            float rs = 0.f;
            union { unsigned u[4]; bf16x8 v; } pu[2];
            #pragma unroll
            for (int ct = 0; ct < 4; ++ct) {
                float p0 = exp2f(st[mt][ct][0]);
                float p1 = exp2f(st[mt][ct][1]);
                float p2 = exp2f(st[mt][ct][2]);
                float p3 = exp2f(st[mt][ct][3]);
                rs += (p0 + p1) + (p2 + p3);
                unsigned lo, hi;
                asm("v_cvt_pk_bf16_f32 %0, %1, %2" : "=v"(lo) : "v"(p0), "v"(p1));
                asm("v_cvt_pk_bf16_f32 %0, %1, %2" : "=v"(hi) : "v"(p2), "v"(p3));
                pu[ct >> 1].u[(ct & 1) * 2 + 0] = lo;
                pu[ct >> 1].u[(ct & 1) * 2 + 1] = hi;
            }
            pB[mt][0] = pu[0].v;
            pB[mt][1] = pu[1].v;
            plsum[mt] += rs;
        }

        // ---- O^T += V^T . P^T  (A = Vt rows, B = in-register P) ----
        __builtin_amdgcn_s_setprio(1);
        #pragma unroll
        for (int ks = 0; ks < 2; ++ks)
            #pragma unroll
            for (int mt = 0; mt < 2; ++mt)
                #pragma unroll
                for (int nt = 0; nt < 4; ++nt)
                    o[mt][nt] = __builtin_amdgcn_mfma_f32_16x16x32_bf16(
                        vf[ks][nt], pB[mt][ks], o[mt][nt], 0, 0, 0);
        __builtin_amdgcn_s_setprio(0);

        // ---- one wait+barrier per iteration: next tile landed, this
        //      tile's reads (all waves) complete before next iter's stage
        VMC0;
        BARR;
    }

    // epilogue: quad-reduce row sums, normalize, float4 stores (4 consec dh)
    #pragma unroll
    for (int mt = 0; mt < 2; ++mt) {
        float l = plsum[mt];
        l += __shfl_xor(l, 16, 64);
        l += __shfl_xor(l, 32, 64);
        float inv = 1.0f / l;
        int srow = qr0 + w * 32 + mt * 16 + lane15;
        float* op = out + (size_t)(b * S + srow) * D + h * DH;
        #pragma unroll
        for (int nt = 0; nt < 4; ++nt) {
            float4 v;
            v.x = o[mt][nt][0] * inv;
            v.y = o[mt][nt][1] * inv;
            v.z = o[mt][nt][2] * inv;
            v.w = o[mt][nt][3] * inv;
            *(float4*)(op + nt * 16 + quad * 4) = v;
        }
    }
}

extern "C" void kernel_launch(void* const* d_in, const int* in_sizes, int n_in,
                              void* d_out, int out_size, void* d_ws, size_t ws_size,
                              hipStream_t stream) {
    const float* x  = (const float*)d_in[0];
    const float* Wq = (const float*)d_in[1];
    const float* Wk = (const float*)d_in[2];
    const float* Wv = (const float*)d_in[3];
    float* outp = (float*)d_out;

    // workspace: [0, 50331648) qkvb bf16 (q,k row-major; v transposed)
    //            [50331648, 67108864) xb bf16; [67108864, 73400320) WbT bf16
    unsigned short* qkvb = (unsigned short*)d_ws;
    unsigned short* xb   = (unsigned short*)((char*)d_ws + 50331648);
    unsigned short* WbT  = (unsigned short*)((char*)d_ws + 67108864);

    convert_x<<<dim3((B * S * D / 4) / 256), 256, 0, stream>>>(x, xb);
    convert_w<<<dim3(D / 64, H, 3), 256, 0, stream>>>(Wq, Wk, Wv, WbT);
    qkv_gemm<<<dim3(B * S / 128, 3 * H * DH / 128), 256, 0, stream>>>(xb, WbT, qkvb);
    attn_mfma<<<dim3(S / 128, BH), 256, 0, stream>>>(qkvb, outp);
}